// Round 4
// baseline (631.850 us; speedup 1.0000x reference)
//
#include <hip/hip_runtime.h>
#include <hip/hip_bf16.h>

// Problem constants
#define B_SZ   16384
#define DIN    2048
#define H1_SZ  512
#define H2_SZ  128
#define N_EXP  8
#define N_CLS  10
#define N1     4608   // 8*512 experts + 512 gate
#define N2     1152   // 8*128 experts + 128 gate

typedef __attribute__((ext_vector_type(8))) __bf16 bf16x8;
typedef __attribute__((ext_vector_type(4))) float  floatx4;
typedef __attribute__((ext_vector_type(4))) short  short4v;
typedef __attribute__((ext_vector_type(8))) short  short8v;

__device__ __forceinline__ float bf2f(short s) {
  unsigned int u = ((unsigned int)(unsigned short)s) << 16;
  float f; __builtin_memcpy(&f, &u, 4); return f;
}

// ---------------------------------------------------------------------------
// Prep 1: features = concat(fs, fp) -> bf16 X[B][DIN]
// ---------------------------------------------------------------------------
__global__ void convert_features_kernel(const float* __restrict__ fs,
                                        const float* __restrict__ fp,
                                        __hip_bfloat16* __restrict__ X) {
  const int nf4 = B_SZ * (DIN / 4);          // 8,388,608 float4 chunks
  const float4* fs4 = (const float4*)fs;
  const float4* fp4 = (const float4*)fp;
  for (int i = blockIdx.x * blockDim.x + threadIdx.x; i < nf4;
       i += gridDim.x * blockDim.x) {
    int c = i & 511;                         // DIN/4 = 512 chunks per row
    int row = i >> 9;
    float4 v = (c < 256) ? fs4[(size_t)row * 256 + c]
                         : fp4[(size_t)row * 256 + (c - 256)];
    union { short4v v4; __hip_bfloat16 h[4]; } u;
    u.h[0] = __float2bfloat16(v.x);
    u.h[1] = __float2bfloat16(v.y);
    u.h[2] = __float2bfloat16(v.z);
    u.h[3] = __float2bfloat16(v.w);
    *(short4v*)(X + (size_t)i * 4) = u.v4;
  }
}

// ---------------------------------------------------------------------------
// Prep 2: transpose-convert weights to B^T layout (rows = n, stride K), bf16.
// ---------------------------------------------------------------------------
__global__ void transpose_convert_kernel(const float* __restrict__ expert_src,
                                         const float* __restrict__ gate_src,
                                         int K, int H, int E,
                                         __hip_bfloat16* __restrict__ out) {
  __shared__ float t[32][33];
  int k0 = blockIdx.x * 32;
  int n0 = blockIdx.y * 32;   // 32 | H, so a tile never straddles experts
  int e = n0 / H;
  const float* src; int h0;
  if (e < E) { src = expert_src + (size_t)e * K * H; h0 = n0 - e * H; }
  else       { src = gate_src;                       h0 = n0 - E * H; }
  int tx = threadIdx.x, ty = threadIdx.y;
  #pragma unroll
  for (int j = 0; j < 4; ++j) {
    int r = ty + j * 8;
    t[r][tx] = src[(size_t)(k0 + r) * H + h0 + tx];
  }
  __syncthreads();
  #pragma unroll
  for (int j = 0; j < 4; ++j) {
    int r = ty + j * 8;
    out[(size_t)(n0 + r) * K + k0 + tx] = __float2bfloat16(t[tx][r]);
  }
}

// ---------------------------------------------------------------------------
// Fused layers 1+2 for one (m-block=64 rows, z-slice) pair. H1 never touches
// HBM: phase 1 computes C1[64][512] = relu(X@W1T[z]+b1) into LDS; phase 2
// computes H2[64][128] = relu(C1@W2T[z]+b2) from LDS.
//   - 512 threads = 8 waves. Phase 1: wave w owns C1 cols [w*64, w*64+64),
//     4x4 tiles of 16x16x32 MFMA, BK=64 (R1-proven XOR-swizzled layout,
//     SQ_LDS_BANK_CONFLICT == 0 measured).
//   - LDS: phase1 As(8K)+Bs(64K)=72K; phase2 C1L(64K, overlays As+Bs after
//     final phase-1 barrier)+Bs2(16K)=80K. 80KB/block -> 2 blocks/CU.
//   - C1L uses the same XOR-of-(row&7) 16B-chunk swizzle, applied at write
//     (epilogue) and read (phase-2 A-fragments); swizzle stays within a
//     wave's own 8-chunk span so no cross-wave overlap.
// ---------------------------------------------------------------------------
__global__ __launch_bounds__(512, 4) void fused12_kernel(
    const __hip_bfloat16* __restrict__ X,
    const __hip_bfloat16* __restrict__ W1T,
    const __hip_bfloat16* __restrict__ W2T,
    const float* __restrict__ eb1, const float* __restrict__ gb1,
    const float* __restrict__ eb2, const float* __restrict__ gb2,
    __hip_bfloat16* __restrict__ H2) {
  extern __shared__ __align__(16) __hip_bfloat16 smem[];   // 81920 B dynamic
  __hip_bfloat16* As  = smem;              // [64][64]   8KB  (phase 1)
  __hip_bfloat16* Bs  = smem + 4096;       // [512][64] 64KB  (phase 1)
  __hip_bfloat16* C1L = smem;              // [64][512] 64KB  (phase 2)
  __hip_bfloat16* Bs2 = smem + 32768;      // [128][64] 16KB  (phase 2)

  const int tid  = threadIdx.x;
  const int lane = tid & 63;
  const int wave = tid >> 6;               // 0..7
  const int lrow  = lane & 15;
  const int lquad = lane >> 4;

  const int z  = blockIdx.x;               // 0..7 experts, 8 = gate
  const int m0 = blockIdx.y * 64;

  const __hip_bfloat16* Ab = X   + (size_t)m0 * DIN;
  const __hip_bfloat16* Bb = W1T + (size_t)z * H1_SZ * DIN;
  const __hip_bfloat16* W2b = W2T + (size_t)z * H2_SZ * H1_SZ;
  const float* bias1 = (z < N_EXP) ? (eb1 + z * H1_SZ) : gb1;
  const float* bias2 = (z < N_EXP) ? (eb2 + z * H2_SZ) : gb2;

  // ------------------ phase 1: C1 = relu(X[64xK] @ W1T[z]^T + b1) ----------
  const int wn = wave * 64;
  floatx4 acc[4][4] = {};

  for (int k0 = 0; k0 < DIN; k0 += 64) {
    // stage A: 512 chunks of 16B (one per thread)
    {
      int mi = tid >> 3, cs = tid & 7, cl = cs ^ (mi & 7);
      __builtin_amdgcn_global_load_lds(
          (const __attribute__((address_space(1))) unsigned int*)(Ab + (size_t)mi * DIN + k0 + cl * 8),
          (__attribute__((address_space(3))) unsigned int*)(As + tid * 8),
          16, 0, 0);
    }
    // stage B: 4096 chunks (8 per thread)
    #pragma unroll
    for (int j = 0; j < 8; ++j) {
      int idx = j * 512 + tid;
      int row = idx >> 3, cs = idx & 7, cl = cs ^ (row & 7);
      __builtin_amdgcn_global_load_lds(
          (const __attribute__((address_space(1))) unsigned int*)(Bb + (size_t)row * DIN + k0 + cl * 8),
          (__attribute__((address_space(3))) unsigned int*)(Bs + idx * 8),
          16, 0, 0);
    }
    __syncthreads();
    #pragma unroll
    for (int ks = 0; ks < 2; ++ks) {
      bf16x8 a[4], b[4];
      #pragma unroll
      for (int t = 0; t < 4; ++t) {
        int ar = t * 16 + lrow;                     // 0..63
        int br = wn + t * 16 + lrow;                // 0..511
        int ca = (ks * 4 + lquad) ^ (ar & 7);
        int cb = (ks * 4 + lquad) ^ (br & 7);
        a[t] = *(const bf16x8*)(As + ar * 64 + ca * 8);
        b[t] = *(const bf16x8*)(Bs + br * 64 + cb * 8);
      }
      #pragma unroll
      for (int mt = 0; mt < 4; ++mt)
        #pragma unroll
        for (int nt = 0; nt < 4; ++nt)
          acc[mt][nt] = __builtin_amdgcn_mfma_f32_16x16x32_bf16(
              a[mt], b[nt], acc[mt][nt], 0, 0, 0);
    }
    __syncthreads();
  }

  // ---- C1 epilogue -> LDS (bias+relu, bf16, XOR chunk swizzle, stride 512)
  // Safe to overlay As/Bs: final barrier above guarantees all reads done.
  #pragma unroll
  for (int nt = 0; nt < 4; ++nt) {
    int col = wn + nt * 16 + lrow;
    float bv = bias1[col];
    #pragma unroll
    for (int mt = 0; mt < 4; ++mt) {
      #pragma unroll
      for (int r = 0; r < 4; ++r) {
        int row = mt * 16 + lquad * 4 + r;          // 0..63
        float v = acc[mt][nt][r] + bv;
        v = v > 0.f ? v : 0.f;
        int cc = (((col >> 3) ^ (row & 7)) << 3) | (col & 7);
        C1L[row * 512 + cc] = __float2bfloat16(v);
      }
    }
  }

  // ------------------ phase 2: H2 = relu(C1[64x512] @ W2T[z]^T + b2) -------
  const int wm2 = (wave >> 2) * 32;     // 0 or 32
  const int wn2 = (wave & 3) * 32;      // 0,32,64,96
  floatx4 acc2[2][2] = {};

  for (int k0 = 0; k0 < H1_SZ; k0 += 64) {          // 8 iterations
    #pragma unroll
    for (int j = 0; j < 2; ++j) {
      int idx = j * 512 + tid;                      // 0..1023
      int row = idx >> 3, cs = idx & 7, cl = cs ^ (row & 7);
      __builtin_amdgcn_global_load_lds(
          (const __attribute__((address_space(1))) unsigned int*)(W2b + (size_t)row * H1_SZ + k0 + cl * 8),
          (__attribute__((address_space(3))) unsigned int*)(Bs2 + idx * 8),
          16, 0, 0);
    }
    __syncthreads();   // first iter also covers the C1L ds_writes above
    #pragma unroll
    for (int ks = 0; ks < 2; ++ks) {
      bf16x8 a2[2], b2[2];
      #pragma unroll
      for (int t = 0; t < 2; ++t) {
        int ar = wm2 + t * 16 + lrow;               // 0..63
        int kch = (k0 >> 3) + ks * 4 + lquad;       // absolute 16B chunk 0..63
        a2[t] = *(const bf16x8*)(C1L + ar * 512 + ((kch ^ (ar & 7)) << 3));
        int br = wn2 + t * 16 + lrow;               // 0..127
        int cb = (ks * 4 + lquad) ^ (br & 7);
        b2[t] = *(const bf16x8*)(Bs2 + br * 64 + cb * 8);
      }
      #pragma unroll
      for (int mt = 0; mt < 2; ++mt)
        #pragma unroll
        for (int nt = 0; nt < 2; ++nt)
          acc2[mt][nt] = __builtin_amdgcn_mfma_f32_16x16x32_bf16(
              a2[mt], b2[nt], acc2[mt][nt], 0, 0, 0);
    }
    __syncthreads();
  }

  // ---- H2 epilogue: bias + relu -> global
  #pragma unroll
  for (int nt = 0; nt < 2; ++nt) {
    int col = wn2 + nt * 16 + lrow;                 // 0..127
    float bv = bias2[col];
    #pragma unroll
    for (int mt = 0; mt < 2; ++mt) {
      #pragma unroll
      for (int r = 0; r < 4; ++r) {
        int row = wm2 + mt * 16 + lquad * 4 + r;    // 0..63
        float v = acc2[mt][nt][r] + bv;
        v = v > 0.f ? v : 0.f;
        H2[(size_t)(m0 + row) * N2 + z * H2_SZ + col] = __float2bfloat16(v);
      }
    }
  }
}

// ---------------------------------------------------------------------------
// Layer 3 fused: gate softmax + expert log_softmax + weighted sum.
// ---------------------------------------------------------------------------
__global__ __launch_bounds__(256) void layer3_kernel(
    const __hip_bfloat16* __restrict__ H2,
    const float* __restrict__ gW3, const float* __restrict__ gb3,
    const float* __restrict__ eW3, const float* __restrict__ eb3,
    float* __restrict__ out, float* __restrict__ gate_out) {
  int tid  = threadIdx.x;
  int j    = tid & 7;
  int rloc = tid >> 3;                             // 0..31
  long row = (long)blockIdx.x * 32 + rloc;
  const __hip_bfloat16* hrow = H2 + row * N2;

  float accg = 0.f;
  float acc[N_CLS];
  #pragma unroll
  for (int c = 0; c < N_CLS; ++c) acc[c] = 0.f;

  #pragma unroll 4
  for (int k8 = 0; k8 < 16; ++k8) {
    short8v hg8 = *(const short8v*)(hrow + N_EXP * H2_SZ + k8 * 8);  // gate block
    short8v he8 = *(const short8v*)(hrow + j * H2_SZ + k8 * 8);      // expert j
    #pragma unroll
    for (int t = 0; t < 8; ++t) {
      int k = k8 * 8 + t;
      float hg = bf2f(hg8[t]);
      float he = bf2f(he8[t]);
      accg += hg * gW3[k * N_EXP + j];
      const float* w = eW3 + (size_t)(j * H2_SZ + k) * N_CLS;
      #pragma unroll
      for (int c = 0; c < N_CLS; ++c) acc[c] += he * w[c];
    }
  }

  // gate softmax across the 8 threads of this row
  float gj = accg + gb3[j];
  float mx = gj;
  mx = fmaxf(mx, __shfl_xor(mx, 1));
  mx = fmaxf(mx, __shfl_xor(mx, 2));
  mx = fmaxf(mx, __shfl_xor(mx, 4));
  float ex = __expf(gj - mx);
  float s = ex;
  s += __shfl_xor(s, 1);
  s += __shfl_xor(s, 2);
  s += __shfl_xor(s, 4);
  float gp = ex / s;

  // expert-local log_softmax over 10 classes
  float lg[N_CLS];
  float lm = -1e30f;
  #pragma unroll
  for (int c = 0; c < N_CLS; ++c) {
    lg[c] = acc[c] + eb3[j * N_CLS + c];
    lm = fmaxf(lm, lg[c]);
  }
  float es = 0.f;
  #pragma unroll
  for (int c = 0; c < N_CLS; ++c) es += __expf(lg[c] - lm);
  float lse = lm + __logf(es);

  float o[N_CLS];
  #pragma unroll
  for (int c = 0; c < N_CLS; ++c) o[c] = gp * (lg[c] - lse);
  #pragma unroll
  for (int c = 0; c < N_CLS; ++c) {
    o[c] += __shfl_xor(o[c], 1);
    o[c] += __shfl_xor(o[c], 2);
    o[c] += __shfl_xor(o[c], 4);
  }

  gate_out[row * N_EXP + j] = gp;
  if (j == 0) {
    #pragma unroll
    for (int c = 0; c < N_CLS; ++c) out[row * N_CLS + c] = o[c];
  }
}

// ---------------------------------------------------------------------------
extern "C" void kernel_launch(void* const* d_in, const int* in_sizes, int n_in,
                              void* d_out, int out_size, void* d_ws, size_t ws_size,
                              hipStream_t stream) {
  const float* fs  = (const float*)d_in[0];
  const float* fp  = (const float*)d_in[1];
  const float* gW1 = (const float*)d_in[2];
  const float* gb1 = (const float*)d_in[3];
  const float* gW2 = (const float*)d_in[4];
  const float* gb2 = (const float*)d_in[5];
  const float* gW3 = (const float*)d_in[6];
  const float* gb3 = (const float*)d_in[7];
  const float* eW1 = (const float*)d_in[8];
  const float* eb1 = (const float*)d_in[9];
  const float* eW2 = (const float*)d_in[10];
  const float* eb2 = (const float*)d_in[11];
  const float* eW3 = (const float*)d_in[12];
  const float* eb3 = (const float*)d_in[13];
  float* out = (float*)d_out;                   // [B,10] then [B,8]

  // workspace layout (bytes):
  //   X   : 0          .. 67,108,864   (B*2048 bf16)
  //   W1T : 67,108,864 .. 85,983,232   (4608*2048 bf16)
  //   W2T : 85,983,232 .. 87,162,880   (1152*512 bf16)
  //   H2  : 87,162,880 .. 124,911,616  (B*1152 bf16)  [no alias: X live in fused12]
  char* ws = (char*)d_ws;
  __hip_bfloat16* X   = (__hip_bfloat16*)ws;
  __hip_bfloat16* W1T = (__hip_bfloat16*)(ws + 67108864);
  __hip_bfloat16* W2T = (__hip_bfloat16*)(ws + 85983232);
  __hip_bfloat16* H2  = (__hip_bfloat16*)(ws + 87162880);

  convert_features_kernel<<<2048, 256, 0, stream>>>(fs, fp, X);
  transpose_convert_kernel<<<dim3(DIN / 32, N1 / 32), dim3(32, 8), 0, stream>>>(
      eW1, gW1, DIN, H1_SZ, N_EXP, W1T);
  transpose_convert_kernel<<<dim3(H1_SZ / 32, N2 / 32), dim3(32, 8), 0, stream>>>(
      eW2, gW2, H1_SZ, H2_SZ, N_EXP, W2T);
  fused12_kernel<<<dim3(N_EXP + 1, B_SZ / 64), 512, 81920, stream>>>(
      X, W1T, W2T, eb1, gb1, eb2, gb2, H2);
  layer3_kernel<<<B_SZ / 32, 256, 0, stream>>>(H2, gW3, gb3, eW3, eb3,
                                               out, out + (size_t)B_SZ * N_CLS);
}

// Round 5
// 612.239 us; speedup vs baseline: 1.0320x; 1.0320x over previous
//
#include <hip/hip_runtime.h>
#include <hip/hip_bf16.h>

// Problem constants
#define B_SZ   16384
#define DIN    2048
#define H1_SZ  512
#define H2_SZ  128
#define N_EXP  8
#define N_CLS  10
#define N1     4608   // 8*512 experts + 512 gate
#define N2     1152   // 8*128 experts + 128 gate

typedef __attribute__((ext_vector_type(8))) __bf16 bf16x8;
typedef __attribute__((ext_vector_type(4))) float  floatx4;
typedef __attribute__((ext_vector_type(4))) short  short4v;
typedef __attribute__((ext_vector_type(8))) short  short8v;

__device__ __forceinline__ float bf2f(short s) {
  unsigned int u = ((unsigned int)(unsigned short)s) << 16;
  float f; __builtin_memcpy(&f, &u, 4); return f;
}

// ---------------------------------------------------------------------------
// Merged prep kernel (one launch instead of three):
//   blocks [0,2048)        : features = concat(fs,fp) -> bf16 X[B][DIN]
//   blocks [2048,11264)    : transpose-convert W1 -> W1T (4608 x 2048)
//   blocks [11264,11840)   : transpose-convert W2 -> W2T (1152 x 512)
// ---------------------------------------------------------------------------
__global__ __launch_bounds__(256) void prep_kernel(
    const float* __restrict__ fs, const float* __restrict__ fp,
    const float* __restrict__ eW1, const float* __restrict__ gW1,
    const float* __restrict__ eW2, const float* __restrict__ gW2,
    __hip_bfloat16* __restrict__ X,
    __hip_bfloat16* __restrict__ W1T,
    __hip_bfloat16* __restrict__ W2T) {
  __shared__ float tbuf[32][33];
  const int b   = blockIdx.x;
  const int tid = threadIdx.x;

  if (b < 2048) {
    // ---- features convert ----
    const int nf4 = B_SZ * (DIN / 4);          // 8,388,608 float4 chunks
    const float4* fs4 = (const float4*)fs;
    const float4* fp4 = (const float4*)fp;
    for (int i = b * 256 + tid; i < nf4; i += 2048 * 256) {
      int c = i & 511;                         // DIN/4 = 512 chunks per row
      int row = i >> 9;
      float4 v = (c < 256) ? fs4[(size_t)row * 256 + c]
                           : fp4[(size_t)row * 256 + (c - 256)];
      union { short4v v4; __hip_bfloat16 h[4]; } u;
      u.h[0] = __float2bfloat16(v.x);
      u.h[1] = __float2bfloat16(v.y);
      u.h[2] = __float2bfloat16(v.z);
      u.h[3] = __float2bfloat16(v.w);
      *(short4v*)(X + (size_t)i * 4) = u.v4;
    }
  } else {
    // ---- weight transpose-convert ----
    const float* esrc; const float* gsrc; __hip_bfloat16* out;
    int K, H, bx, by;
    if (b < 2048 + 9216) {
      int t = b - 2048;  bx = t & 63; by = t >> 6;   // 64 x 144 tiles
      esrc = eW1; gsrc = gW1; out = W1T; K = DIN; H = H1_SZ;
    } else {
      int t = b - 11264; bx = t & 15; by = t >> 4;   // 16 x 36 tiles
      esrc = eW2; gsrc = gW2; out = W2T; K = H1_SZ; H = H2_SZ;
    }
    int k0 = bx * 32, n0 = by * 32;   // 32 | H, tile never straddles experts
    int e = n0 / H;
    const float* src; int h0;
    if (e < N_EXP) { src = esrc + (size_t)e * K * H; h0 = n0 - e * H; }
    else           { src = gsrc;                     h0 = n0 - N_EXP * H; }
    int tx = tid & 31, ty = tid >> 5;
    #pragma unroll
    for (int j = 0; j < 4; ++j) {
      int r = ty + j * 8;
      tbuf[r][tx] = src[(size_t)(k0 + r) * H + h0 + tx];
    }
    __syncthreads();
    #pragma unroll
    for (int j = 0; j < 4; ++j) {
      int r = ty + j * 8;
      out[(size_t)(n0 + r) * K + k0 + tx] = __float2bfloat16(tbuf[tx][r]);
    }
  }
}

// ---------------------------------------------------------------------------
// MFMA GEMM core: C[128x128] = relu(A[128xK] * B[KxN-slice] + bias), bf16 out.
// XOR-swizzled LDS (R1: SQ_LDS_BANK_CONFLICT == 0 measured). Plain cached
// stores (R3: nontemporal stores regressed -- 2B strided NT defeats L2 write
// combining).
// ---------------------------------------------------------------------------
__device__ __forceinline__ void gemm_core(
    const __hip_bfloat16* __restrict__ A,  int lda,
    const __hip_bfloat16* __restrict__ BT, int K,
    const float* __restrict__ bias,
    __hip_bfloat16* __restrict__ O, int ldo) {
  __shared__ __align__(16) __hip_bfloat16 As[128 * 64];
  __shared__ __align__(16) __hip_bfloat16 Bs[128 * 64];

  const int tid  = threadIdx.x;
  const int lane = tid & 63;
  const int wave = tid >> 6;
  const int wm   = (wave >> 1) * 64;
  const int wn   = (wave & 1) * 64;
  const int lrow  = lane & 15;
  const int lquad = lane >> 4;

  floatx4 acc[4][4] = {};

  for (int k0 = 0; k0 < K; k0 += 64) {
    #pragma unroll
    for (int j = 0; j < 4; ++j) {
      int chunk = j * 256 + tid;       // 0..1023 chunks of 8 bf16 (16 B)
      int mi = chunk >> 3;             // tile row 0..127
      int cs = chunk & 7;              // stored chunk slot 0..7
      int cl = cs ^ (mi & 7);          // logical k-chunk held in this slot
      __builtin_amdgcn_global_load_lds(
          (const __attribute__((address_space(1))) unsigned int*)(A + (size_t)mi * lda + k0 + cl * 8),
          (__attribute__((address_space(3))) unsigned int*)(As + chunk * 8),
          16, 0, 0);
      __builtin_amdgcn_global_load_lds(
          (const __attribute__((address_space(1))) unsigned int*)(BT + (size_t)mi * K + k0 + cl * 8),
          (__attribute__((address_space(3))) unsigned int*)(Bs + chunk * 8),
          16, 0, 0);
    }
    __syncthreads();
    #pragma unroll
    for (int ks = 0; ks < 2; ++ks) {
      bf16x8 a[4], b[4];
      #pragma unroll
      for (int t = 0; t < 4; ++t) {
        int ar = wm + t * 16 + lrow;
        int br = wn + t * 16 + lrow;
        int ca = (ks * 4 + lquad) ^ (ar & 7);   // swizzled chunk slot
        int cb = (ks * 4 + lquad) ^ (br & 7);
        a[t] = *(const bf16x8*)(As + ar * 64 + ca * 8);
        b[t] = *(const bf16x8*)(Bs + br * 64 + cb * 8);
      }
      #pragma unroll
      for (int mt = 0; mt < 4; ++mt)
        #pragma unroll
        for (int nt = 0; nt < 4; ++nt)
          acc[mt][nt] = __builtin_amdgcn_mfma_f32_16x16x32_bf16(
              a[mt], b[nt], acc[mt][nt], 0, 0, 0);
    }
    __syncthreads();
  }

  // epilogue: bias + relu -> bf16. C/D layout: col = lane&15, row = quad*4+r.
  #pragma unroll
  for (int nt = 0; nt < 4; ++nt) {
    int col = wn + nt * 16 + lrow;
    float bv = bias[col];
    #pragma unroll
    for (int mt = 0; mt < 4; ++mt) {
      #pragma unroll
      for (int r = 0; r < 4; ++r) {
        int row = wm + mt * 16 + lquad * 4 + r;
        float v = acc[mt][nt][r] + bv;
        v = v > 0.f ? v : 0.f;
        O[(size_t)row * ldo + col] = __float2bfloat16(v);
      }
    }
  }
}

// Layer 1: X[B][2048] @ W1T^T -> relu -> H1[B][4608]
// Grid launched as (x = m-tiles 128, y = n-tiles 36): linear block id is
// x-major, XCD assignment is round-robin (id % 8), so one XCD's co-resident
// blocks share the SAME n-tile (same 512 KB B-slice) at nearby m -> B stays
// L2-resident per XCD. (R2 FETCH was 611 MB vs 86 MB of distinct input.)
__global__ __launch_bounds__(256, 4) void gemm1_kernel(
    const __hip_bfloat16* __restrict__ X, const __hip_bfloat16* __restrict__ W1T,
    const float* __restrict__ eb1, const float* __restrict__ gb1,
    __hip_bfloat16* __restrict__ H1) {
  int m0 = blockIdx.x * 128;
  int n0 = blockIdx.y * 128;
  const float* bias = (n0 < N_EXP * H1_SZ) ? (eb1 + n0) : (gb1 + (n0 - N_EXP * H1_SZ));
  gemm_core(X + (size_t)m0 * DIN, DIN,
            W1T + (size_t)n0 * DIN, DIN,
            bias,
            H1 + (size_t)m0 * N1 + n0, N1);
}

// Layer 2: per z in 0..8: H1 block [B][512] @ W2T[z]^T -> relu -> H2 [B][128]
__global__ __launch_bounds__(256, 4) void gemm2_kernel(
    const __hip_bfloat16* __restrict__ H1, const __hip_bfloat16* __restrict__ W2T,
    const float* __restrict__ eb2, const float* __restrict__ gb2,
    __hip_bfloat16* __restrict__ H2) {
  int m0 = blockIdx.y * 128;
  int z  = blockIdx.z;                 // 0..7 experts, 8 = gate
  const float* bias = (z < N_EXP) ? (eb2 + z * H2_SZ) : gb2;
  gemm_core(H1 + (size_t)m0 * N1 + z * H1_SZ, N1,
            W2T + (size_t)z * H2_SZ * H1_SZ, H1_SZ,
            bias,
            H2 + (size_t)m0 * N2 + z * H2_SZ, N2);
}

// ---------------------------------------------------------------------------
// Layer 3 fused: gate softmax + expert log_softmax + weighted sum.
// ---------------------------------------------------------------------------
__global__ __launch_bounds__(256) void layer3_kernel(
    const __hip_bfloat16* __restrict__ H2,
    const float* __restrict__ gW3, const float* __restrict__ gb3,
    const float* __restrict__ eW3, const float* __restrict__ eb3,
    float* __restrict__ out, float* __restrict__ gate_out) {
  int tid  = threadIdx.x;
  int j    = tid & 7;
  int rloc = tid >> 3;                             // 0..31
  long row = (long)blockIdx.x * 32 + rloc;
  const __hip_bfloat16* hrow = H2 + row * N2;

  float accg = 0.f;
  float acc[N_CLS];
  #pragma unroll
  for (int c = 0; c < N_CLS; ++c) acc[c] = 0.f;

  #pragma unroll 4
  for (int k8 = 0; k8 < 16; ++k8) {
    short8v hg8 = *(const short8v*)(hrow + N_EXP * H2_SZ + k8 * 8);  // gate block
    short8v he8 = *(const short8v*)(hrow + j * H2_SZ + k8 * 8);      // expert j
    #pragma unroll
    for (int t = 0; t < 8; ++t) {
      int k = k8 * 8 + t;
      float hg = bf2f(hg8[t]);
      float he = bf2f(he8[t]);
      accg += hg * gW3[k * N_EXP + j];
      const float* w = eW3 + (size_t)(j * H2_SZ + k) * N_CLS;
      #pragma unroll
      for (int c = 0; c < N_CLS; ++c) acc[c] += he * w[c];
    }
  }

  // gate softmax across the 8 threads of this row
  float gj = accg + gb3[j];
  float mx = gj;
  mx = fmaxf(mx, __shfl_xor(mx, 1));
  mx = fmaxf(mx, __shfl_xor(mx, 2));
  mx = fmaxf(mx, __shfl_xor(mx, 4));
  float ex = __expf(gj - mx);
  float s = ex;
  s += __shfl_xor(s, 1);
  s += __shfl_xor(s, 2);
  s += __shfl_xor(s, 4);
  float gp = ex / s;

  // expert-local log_softmax over 10 classes
  float lg[N_CLS];
  float lm = -1e30f;
  #pragma unroll
  for (int c = 0; c < N_CLS; ++c) {
    lg[c] = acc[c] + eb3[j * N_CLS + c];
    lm = fmaxf(lm, lg[c]);
  }
  float es = 0.f;
  #pragma unroll
  for (int c = 0; c < N_CLS; ++c) es += __expf(lg[c] - lm);
  float lse = lm + __logf(es);

  float o[N_CLS];
  #pragma unroll
  for (int c = 0; c < N_CLS; ++c) o[c] = gp * (lg[c] - lse);
  #pragma unroll
  for (int c = 0; c < N_CLS; ++c) {
    o[c] += __shfl_xor(o[c], 1);
    o[c] += __shfl_xor(o[c], 2);
    o[c] += __shfl_xor(o[c], 4);
  }

  gate_out[row * N_EXP + j] = gp;
  if (j == 0) {
    #pragma unroll
    for (int c = 0; c < N_CLS; ++c) out[row * N_CLS + c] = o[c];
  }
}

// ---------------------------------------------------------------------------
extern "C" void kernel_launch(void* const* d_in, const int* in_sizes, int n_in,
                              void* d_out, int out_size, void* d_ws, size_t ws_size,
                              hipStream_t stream) {
  const float* fs  = (const float*)d_in[0];
  const float* fp  = (const float*)d_in[1];
  const float* gW1 = (const float*)d_in[2];
  const float* gb1 = (const float*)d_in[3];
  const float* gW2 = (const float*)d_in[4];
  const float* gb2 = (const float*)d_in[5];
  const float* gW3 = (const float*)d_in[6];
  const float* gb3 = (const float*)d_in[7];
  const float* eW1 = (const float*)d_in[8];
  const float* eb1 = (const float*)d_in[9];
  const float* eW2 = (const float*)d_in[10];
  const float* eb2 = (const float*)d_in[11];
  const float* eW3 = (const float*)d_in[12];
  const float* eb3 = (const float*)d_in[13];
  float* out = (float*)d_out;                   // [B,10] then [B,8]

  // workspace layout (bytes):
  //   X   : 0          .. 67,108,864   (B*2048 bf16)  -- aliased by H2 later
  //   W1T : 67,108,864 .. 85,983,232   (4608*2048 bf16)
  //   W2T : 85,983,232 .. 87,162,880   (1152*512 bf16)
  //   H1  : 87,162,880 .. 238,157,824  (B*4608 bf16)
  char* ws = (char*)d_ws;
  __hip_bfloat16* X   = (__hip_bfloat16*)ws;
  __hip_bfloat16* H2  = X;   // alias: X dead after gemm1, H2 fits inside
  __hip_bfloat16* W1T = (__hip_bfloat16*)(ws + 67108864);
  __hip_bfloat16* W2T = (__hip_bfloat16*)(ws + 85983232);
  __hip_bfloat16* H1  = (__hip_bfloat16*)(ws + 87162880);

  prep_kernel<<<11840, 256, 0, stream>>>(fs, fp, eW1, gW1, eW2, gW2, X, W1T, W2T);
  gemm1_kernel<<<dim3(B_SZ / 128, N1 / 128), 256, 0, stream>>>(X, W1T, eb1, gb1, H1);
  gemm2_kernel<<<dim3(1, B_SZ / 128, N_EXP + 1), 256, 0, stream>>>(H1, W2T, eb2, gb2, H2);
  layer3_kernel<<<B_SZ / 32, 256, 0, stream>>>(H2, gW3, gb3, eW3, eb3,
                                               out, out + (size_t)B_SZ * N_CLS);
}